// Round 4
// baseline (675.624 us; speedup 1.0000x reference)
//
#include <hip/hip_runtime.h>

// RouteNet (f32 in / f32 out): BN(x) -> 2 input GEMMs -> 16-bank gated graph with
// per-bank BN -> output GEMM. Round 4: VALU-f32 input GEMM (MFMA path removed to
// bisect the ~70-absmax bug). acts stored RAW (post-relu, pre-BN) in ws; BN applied
// on the fly from per-bank stats. BN folded into B' = scale*W_in, bias' = b_in + shift@W_in.

#define BATCH 8192
#define NIN 3072
#define DD 32
#define NB 16
#define NOUT 1000
#define TGOFF (BATCH * NOUT)
#define BNEPS 1e-5f

// ws float offsets
#define O_SUM 0          // [3072] column sums of x
#define O_SUM2 3072      // [3072] column sums of x^2
#define O_STATS 6144     // [16][64] per-bank (sum[32], sumsq[32])
#define O_TG 7168        // [8192] total_gate accumulator (f32)
#define ZERO_FLOATS 15360
#define O_SCALE 15360    // [3072]
#define O_SHIFT 18432    // [3072]
#define O_BIAS 21504     // [64] fused bias for input banks
#define O_BP 21568       // [3072][64] f32 folded B'  (196608 floats)
#define O_ACTS 218176    // [16][8192][32] raw acts (f32)
// total ws floats = 218176 + 16*8192*32 = 4,412,480  (~16.8 MB)

// ---- K1: column stats of x (sum, sumsq) ----
__global__ void __launch_bounds__(256) k_stats(const float* __restrict__ x, float* __restrict__ ws) {
    int c = blockIdx.x * 256 + threadIdx.x;            // 12 x-blocks cover 3072 cols
    const float* p = x + (size_t)blockIdx.y * 64 * NIN + c;  // 128 y-blocks x 64 rows
    float s = 0.f, s2 = 0.f;
#pragma unroll 8
    for (int i = 0; i < 64; i++) { float v = p[(size_t)i * NIN]; s += v; s2 += v * v; }
    atomicAdd(&ws[O_SUM + c], s);
    atomicAdd(&ws[O_SUM2 + c], s2);
}

// ---- K2: scale/shift from stats; init fused bias with b_in ----
__global__ void __launch_bounds__(256) k_prep(float* __restrict__ ws, const float* __restrict__ g,
                                              const float* __restrict__ b, const float* __restrict__ b_in) {
    int c = blockIdx.x * 256 + threadIdx.x;
    float mean = ws[O_SUM + c] * (1.f / BATCH);
    float var = ws[O_SUM2 + c] * (1.f / BATCH) - mean * mean;
    float sc = g[c] * rsqrtf(fmaxf(var, 0.f) + BNEPS);
    ws[O_SCALE + c] = sc;
    ws[O_SHIFT + c] = b[c] - mean * sc;
    if (c < 64) ws[O_BIAS + c] = b_in[c];
}

// ---- K3a: fused bias += shift @ W_in  (per bank) ----
__global__ void __launch_bounds__(256) k_bias(float* __restrict__ ws, const float* __restrict__ W_in) {
    int bank = blockIdx.x & 1, jc = blockIdx.x >> 1;   // 12 j-chunks of 256
    int d = threadIdx.x & 31, js = threadIdx.x >> 5;
    int j0 = jc * 256 + js * 32;
    float a = 0.f;
    for (int j = 0; j < 32; j++) {
        float sh = ws[O_SHIFT + j0 + j];
        a += sh * W_in[(size_t)bank * NIN * DD + (size_t)(j0 + j) * DD + d];
    }
    __shared__ float red[8][32];
    red[js][d] = a;
    __syncthreads();
    if (threadIdx.x < 32) {
        float t = 0.f;
#pragma unroll
        for (int g8 = 0; g8 < 8; g8++) t += red[g8][threadIdx.x];
        atomicAdd(&ws[O_BIAS + bank * 32 + threadIdx.x], t);
    }
}

// ---- K3b: fold BN scale into weights: B'[j][c] = scale[j] * W_in[c>>5][j][c&31] ----
__global__ void __launch_bounds__(256) k_bfold(float* __restrict__ ws, const float* __restrict__ W_in) {
    int idx = blockIdx.x * 256 + threadIdx.x;          // 768 blocks -> 196608
    int j = idx >> 6, c = idx & 63;
    ws[O_BP + idx] = ws[O_SCALE + j] * W_in[(size_t)(c >> 5) * NIN * DD + (size_t)j * DD + (c & 31)];
}

// ---- K4: input GEMM (VALU f32), M=8192 K=3072 N=64. 256 blocks x 32 rows. ----
__global__ void __launch_bounds__(256) k_gemm_valu(const float* __restrict__ x, float* __restrict__ ws) {
    __shared__ float xL[32][36];     // pad to 36 (16B-aligned rows, conflict-free)
    __shared__ float bL[32][64];
    int tid = threadIdx.x;
    int tx = tid & 15, ty = tid >> 4;
    int c0 = tx * 4;
    int row0 = blockIdx.x * 32;
    const float* bp = ws + O_BP;
    float acc0[4] = {0.f, 0.f, 0.f, 0.f};
    float acc1[4] = {0.f, 0.f, 0.f, 0.f};
    int sr = tid >> 3, sq = (tid & 7) * 4;
    for (int kc = 0; kc < 96; kc++) {
        int k0 = kc * 32;
        float4 xv = *(const float4*)&x[(size_t)(row0 + sr) * NIN + k0 + sq];
        float4 b0 = *(const float4*)&bp[(size_t)(k0 + sr) * 64 + sq * 2];
        float4 b1 = *(const float4*)&bp[(size_t)(k0 + sr) * 64 + sq * 2 + 4];
        *(float4*)&xL[sr][sq] = xv;
        *(float4*)&bL[sr][sq * 2] = b0;
        *(float4*)&bL[sr][sq * 2 + 4] = b1;
        __syncthreads();
#pragma unroll
        for (int k = 0; k < 32; k++) {
            float4 bv = *(float4*)&bL[k][c0];
            float xa = xL[ty * 2][k];
            float xb = xL[ty * 2 + 1][k];
            acc0[0] += xa * bv.x; acc0[1] += xa * bv.y; acc0[2] += xa * bv.z; acc0[3] += xa * bv.w;
            acc1[0] += xb * bv.x; acc1[1] += xb * bv.y; acc1[2] += xb * bv.z; acc1[3] += xb * bv.w;
        }
        __syncthreads();
    }
    int rg0 = row0 + ty * 2;
#pragma unroll
    for (int j = 0; j < 4; j++) {
        int c = c0 + j;
        float bias = ws[O_BIAS + c];
        int bank = c >> 5, dd = c & 31;
        float v0 = fmaxf(acc0[j] + bias, 0.f);
        float v1 = fmaxf(acc1[j] + bias, 0.f);
        ws[O_ACTS + ((size_t)bank * BATCH + rg0) * DD + dd] = v0;
        ws[O_ACTS + ((size_t)bank * BATCH + rg0 + 1) * DD + dd] = v1;
    }
}

// ---- K5 (x16): one bank of the graph. Sources normalized on the fly from stats. ----
__global__ void __launch_bounds__(256) k_bank(int t, float* __restrict__ ws,
                                              const float* __restrict__ Wg, const float* __restrict__ Wd,
                                              const float* __restrict__ bd) {
    __shared__ float asrcL[4][32][32];
    __shared__ float curL[32][32];
    __shared__ float WdL[32][32];
    __shared__ float red[8][64];
    int tid = threadIdx.x;
    int rg = tid >> 5, d = tid & 31;
    int row0 = blockIdx.x * 32;
    float* acts = ws + O_ACTS;
    const float* stats = ws + O_STATS;
    int nE = t < 4 ? t : 4;
    int s0 = t - nE;
    int eb = (t <= 4) ? (t * (t - 1)) / 2 : (10 + 4 * (t - 5));
    for (int si = 0; si < nE; si++) {
        int s = s0 + si;
        float m = stats[s * 64 + d] * (1.f / BATCH);
        float q = stats[s * 64 + 32 + d] * (1.f / BATCH);
        float iv = rsqrtf(fmaxf(q - m * m, 0.f) + BNEPS);
#pragma unroll
        for (int c = 0; c < 4; c++) {
            int r = c * 8 + rg;
            asrcL[si][r][d] = (acts[((size_t)s * BATCH + row0 + r) * DD + d] - m) * iv;
        }
    }
#pragma unroll
    for (int c = 0; c < 4; c++) {
        int r = c * 8 + rg;
        curL[r][d] = (t < 2) ? acts[((size_t)t * BATCH + row0 + r) * DD + d] : 0.f;
    }
    __syncthreads();
    float tgs[4] = {0.f, 0.f, 0.f, 0.f};
    for (int ei = 0; ei < nE; ei++) {
        int e = eb + ei;
        ((float4*)WdL)[tid] = ((const float4*)(Wd + (size_t)e * 1024))[tid];
        __syncthreads();
        float wg = Wg[e * 32 + d];
        float bde = bd[e * 32 + d];
#pragma unroll
        for (int c = 0; c < 4; c++) {
            int r = c * 8 + rg;
            float g = asrcL[ei][r][d] * wg;
            g += __shfl_xor(g, 16, 32); g += __shfl_xor(g, 8, 32); g += __shfl_xor(g, 4, 32);
            g += __shfl_xor(g, 2, 32);  g += __shfl_xor(g, 1, 32);
            g = fminf(fmaxf(g, 0.f), 1.f);
            tgs[c] += g;
            float dat = bde;
#pragma unroll
            for (int k = 0; k < 32; k++) dat += asrcL[ei][r][k] * WdL[k][d];
            curL[r][d] += g * dat;
        }
        __syncthreads();
    }
    float s1 = 0.f, s2 = 0.f;
#pragma unroll
    for (int c = 0; c < 4; c++) {
        int r = c * 8 + rg;
        float v = fmaxf(curL[r][d], 0.f);
        acts[((size_t)t * BATCH + row0 + r) * DD + d] = v;
        s1 += v; s2 += v * v;
    }
    red[rg][d] = s1; red[rg][32 + d] = s2;
    __syncthreads();
    if (tid < 64) {
        float a = 0.f;
#pragma unroll
        for (int g8 = 0; g8 < 8; g8++) a += red[g8][tid];
        atomicAdd(&ws[O_STATS + t * 64 + tid], a);
    }
    if (d == 0) {
#pragma unroll
        for (int c = 0; c < 4; c++) ws[O_TG + row0 + c * 8 + rg] += tgs[c];
    }
}

// ---- K6: output GEMM [8192x64] @ [64x1000] -> f32; also emit total_gate f32 ----
__global__ void __launch_bounds__(256) k_out(const float* __restrict__ ws,
                                             const float* __restrict__ Wout,
                                             float* __restrict__ out) {
    __shared__ float aL[2][32][32];
    __shared__ float wl[2][32][128];
    int tid = threadIdx.x;
    int rg = tid >> 5, d = tid & 31;
    int row0 = blockIdx.x * 32;
    const float* acts = ws + O_ACTS;
    const float* stats = ws + O_STATS;
    if (tid < 32) out[TGOFF + row0 + tid] = ws[O_TG + row0 + tid];
#pragma unroll
    for (int bi = 0; bi < 2; bi++) {
        int s = 14 + bi;
        float m = stats[s * 64 + d] * (1.f / BATCH);
        float q = stats[s * 64 + 32 + d] * (1.f / BATCH);
        float iv = rsqrtf(fmaxf(q - m * m, 0.f) + BNEPS);
#pragma unroll
        for (int c = 0; c < 4; c++) {
            int r = c * 8 + rg;
            aL[bi][r][d] = (acts[((size_t)s * BATCH + row0 + r) * DD + d] - m) * iv;
        }
    }
    __syncthreads();
    int nn = tid & 127, half = tid >> 7;
    for (int nc = 0; nc < 8; nc++) {
        int n = nc * 128 + nn;
        for (int i = 0; i < 32; i++) {
            int kbk = i * 2 + half;
            int kb = kbk >> 5, k = kbk & 31;
            if (n < NOUT) wl[kb][k][nn] = Wout[(size_t)kb * DD * NOUT + (size_t)k * NOUT + n];
        }
        __syncthreads();
#pragma unroll
        for (int rc = 0; rc < 2; rc++) {
            int rb = half * 16 + rc * 8;
            float acc[8] = {0.f,0.f,0.f,0.f,0.f,0.f,0.f,0.f};
            for (int k = 0; k < 32; k++) {
                float w0 = wl[0][k][nn], w1 = wl[1][k][nn];
#pragma unroll
                for (int rr = 0; rr < 8; rr++)
                    acc[rr] += aL[0][rb + rr][k] * w0 + aL[1][rb + rr][k] * w1;
            }
            if (n < NOUT) {
#pragma unroll
                for (int rr = 0; rr < 8; rr++)
                    out[(size_t)(row0 + rb + rr) * NOUT + n] = acc[rr];
            }
        }
        __syncthreads();
    }
}

extern "C" void kernel_launch(void* const* d_in, const int* in_sizes, int n_in,
                              void* d_out, int out_size, void* d_ws, size_t ws_size,
                              hipStream_t stream) {
    (void)in_sizes; (void)n_in; (void)out_size; (void)ws_size;
    const float* x     = (const float*)d_in[0];
    const float* gamma = (const float*)d_in[1];
    const float* beta  = (const float*)d_in[2];
    const float* W_in  = (const float*)d_in[3];
    const float* b_in  = (const float*)d_in[4];
    const float* Wg    = (const float*)d_in[5];
    const float* Wd    = (const float*)d_in[6];
    const float* bd    = (const float*)d_in[7];
    const float* Wout  = (const float*)d_in[8];
    float* out = (float*)d_out;
    float* ws  = (float*)d_ws;

    hipMemsetAsync(d_ws, 0, ZERO_FLOATS * sizeof(float), stream);
    k_stats<<<dim3(12, 128), 256, 0, stream>>>(x, ws);
    k_prep<<<12, 256, 0, stream>>>(ws, gamma, beta, b_in);
    k_bias<<<24, 256, 0, stream>>>(ws, W_in);
    k_bfold<<<768, 256, 0, stream>>>(ws, W_in);
    k_gemm_valu<<<256, 256, 0, stream>>>(x, ws);
    for (int t = 0; t < NB; t++)
        k_bank<<<256, 256, 0, stream>>>(t, ws, Wg, Wd, bd);
    k_out<<<256, 256, 0, stream>>>(ws, Wout, out);
}